// Round 1
// baseline (190.322 us; speedup 1.0000x reference)
//
#include <hip/hip_runtime.h>

#define B_ 4096
#define S_ 512
#define D_ 18
#define V_ 100000
#define EPS_ 1e-7f

// One wave (64 lanes) per batch; 4 batches per 256-thread block.
// Lane l handles positions s = base + l, base += 64 while base < cnt.
// A[s] = mb[s]*xr[s], L[s] = mb[s]*xl[s] (per-dim).
//   hdiff[s] = 0.5*(A+L) - head*mb         (mask 1 <= s < cnt)
//   vdiff[s-1] = A[s-1] - L[s]             (mask 2 <= s < cnt)
// A[s-1] comes from __shfl_up(1); lane 0 gets the previous tile's lane-63 A
// via an 18-reg carry broadcast.
__global__ __launch_bounds__(256) void emb_kernel(
    const int* __restrict__ mids,
    const int* __restrict__ wids,
    const int* __restrict__ cnts,
    const float* __restrict__ mc,
    const float* __restrict__ xlt,
    const float* __restrict__ xrt,
    float* __restrict__ out)
{
    __shared__ float mc_lds[D_ * D_];
    for (int i = threadIdx.x; i < D_ * D_; i += 256) mc_lds[i] = mc[i];
    __syncthreads();

    const int wave = threadIdx.x >> 6;
    const int lane = threadIdx.x & 63;
    const int b = blockIdx.x * 4 + wave;
    const int cnt = cnts[b];
    const int base_idx = b * S_;

    // head = xl_table[wids[b,0]] -- uniform per wave, every lane keeps a copy
    const int wid0 = wids[base_idx];
    float head[D_];
    #pragma unroll
    for (int d = 0; d < D_; ++d) head[d] = xlt[wid0 * D_ + d];

    float vsum[D_], hsum[D_], Acarry[D_];
    #pragma unroll
    for (int d = 0; d < D_; ++d) { vsum[d] = 0.f; hsum[d] = 0.f; Acarry[d] = 0.f; }

    for (int base = 0; base < cnt; base += 64) {
        const int s = base + lane;
        const bool active = (s < cnt);
        const int idx = base_idx + s;           // s < S_ always (S_ % 64 == 0)
        const int wid = active ? wids[idx] : 0; // row 0 is valid memory
        const int mid = active ? mids[idx] : 0;
        const float hf = (active && s >= 1) ? 1.0f : 0.0f;
        const float vf = (active && s >= 2) ? 1.0f : 0.0f;

        const float2* xlp = (const float2*)(xlt + (size_t)wid * D_);
        const float2* xrp = (const float2*)(xrt + (size_t)wid * D_);
        const float2* mp  = (const float2*)(mc_lds + mid * D_);

        float A[D_];
        #pragma unroll
        for (int p = 0; p < D_ / 2; ++p) {
            const float2 xl2 = xlp[p];
            const float2 xr2 = xrp[p];
            const float2 m2  = mp[p];
            const float mm[2] = { m2.x,  m2.y  };
            const float ll[2] = { xl2.x, xl2.y };
            const float rr[2] = { xr2.x, xr2.y };
            #pragma unroll
            for (int q = 0; q < 2; ++q) {
                const int d = 2 * p + q;
                const float Ad = mm[q] * rr[q];
                const float Ld = mm[q] * ll[q];
                A[d] = Ad;
                // hdiff = 0.5*(A+L) - head*m
                const float hd = fmaf(-head[d], mm[q], 0.5f * (Ad + Ld));
                hsum[d] = fmaf(hd * hf, hd, hsum[d]);
                // vdiff for index s-1: A[s-1] - L[s]
                float Ap = __shfl_up(Ad, 1);
                if (lane == 0) Ap = Acarry[d];
                const float vd = Ap - Ld;
                vsum[d] = fmaf(vd * vf, vd, vsum[d]);
            }
        }
        #pragma unroll
        for (int d = 0; d < D_; ++d) Acarry[d] = __shfl(A[d], 63);
    }

    // butterfly reduce 36 accumulators across the wave
    #pragma unroll
    for (int off = 32; off >= 1; off >>= 1) {
        #pragma unroll
        for (int d = 0; d < D_; ++d) {
            vsum[d] += __shfl_xor(vsum[d], off);
            hsum[d] += __shfl_xor(hsum[d], off);
        }
    }

    if (lane == 0) {
        const float inv = 1.0f / ((float)cnt + EPS_);
        #pragma unroll
        for (int d = 0; d < D_; ++d) {
            const float o1 = sqrtf(vsum[d] * inv);
            const float o2 = sqrtf(hsum[d] * inv);
            out[(size_t)b * D_ + d] = 0.5f * (o1 + o2);
            out[(size_t)B_ * D_ + (size_t)b * D_ + d] = head[d];
        }
    }
}

extern "C" void kernel_launch(void* const* d_in, const int* in_sizes, int n_in,
                              void* d_out, int out_size, void* d_ws, size_t ws_size,
                              hipStream_t stream) {
    const int*   mids = (const int*)d_in[0];
    const int*   wids = (const int*)d_in[1];
    const int*   cnts = (const int*)d_in[2];
    const float* mc   = (const float*)d_in[3];
    const float* xlt  = (const float*)d_in[4];
    const float* xrt  = (const float*)d_in[5];
    float* out = (float*)d_out;

    dim3 grid(B_ / 4), block(256);
    hipLaunchKernelGGL(emb_kernel, grid, block, 0, stream,
                       mids, wids, cnts, mc, xlt, xrt, out);
}